// Round 5
// baseline (300.681 us; speedup 1.0000x reference)
//
#include <hip/hip_runtime.h>

// Problem constants (fixed by the reference).
#define N_NODES 50000
#define N_EDGES 800000
#define X_DIM 128
#define H_DIM 256
#define Y_DIM 128

typedef unsigned int uint32;
typedef unsigned short ushort16;
typedef __attribute__((ext_vector_type(8))) short short8;
typedef __attribute__((ext_vector_type(4))) float floatx4;

// bf16 helpers (round-to-nearest-even)
__device__ inline ushort16 f2bf(float f) {
    uint32 u = __float_as_uint(f);
    return (ushort16)((u + 0x7FFFu + ((u >> 16) & 1u)) >> 16);
}
__device__ inline float bf_lo(uint32 u) { return __uint_as_float(u << 16); }
__device__ inline float bf_hi(uint32 u) { return __uint_as_float(u & 0xFFFF0000u); }

// Bucket geometry: 391 buckets of 128 rows; 196 chunks of 4096 edges.
#define BUCKET_SHIFT 7
#define NB 391              // ceil(50000/128)
#define CHUNK 4096
#define NCHUNK 196          // ceil(800000/4096)
#define CAP_B 2560          // LDS capacity per bucket (mean 2046)

#define NORM_BLOCKS 12500   // N_NODES*64/256
#define CONV_BLOCKS 256     // 65536/256

// ---------------------------------------------------------------------------
// Prep (fused): row-normalize x -> bf16; transpose-convert W1,W2 to bf16;
// per-chunk bucket histograms -> gpartial[chunk][bucket] (no global atomics).
// ---------------------------------------------------------------------------
__global__ __launch_bounds__(256) void prep_kernel(
    const float* __restrict__ x, uint32* __restrict__ xb,
    const float* __restrict__ W1, const float* __restrict__ W2,
    ushort16* __restrict__ W1t, ushort16* __restrict__ W2t,
    const int* __restrict__ rows, int* __restrict__ gpartial) {
    int b = blockIdx.x;
    if (b < NORM_BLOCKS) {
        int row = (b * 256 + threadIdx.x) >> 6;  // exact: 12500*4 = 50000 rows
        int lane = threadIdx.x & 63;
        float2 v = ((const float2*)x)[(size_t)row * 64 + lane];
        float s = v.x + v.y;
        #pragma unroll
        for (int off = 32; off > 0; off >>= 1) s += __shfl_xor(s, off, 64);
        float inv = 1.0f / (s + 1e-4f);
        uint32 lo = (uint32)f2bf(v.x * inv);
        uint32 hi = (uint32)f2bf(v.y * inv);
        xb[(size_t)row * 64 + lane] = lo | (hi << 16);
    } else if (b < NORM_BLOCKS + CONV_BLOCKS) {
        int t = (b - NORM_BLOCKS) * 256 + threadIdx.x;  // 0..65535
        if (t < X_DIM * H_DIM) {
            int n = t >> 7, k = t & 127;           // W1t[n][k] = W1[k][n]
            W1t[t] = f2bf(W1[k * H_DIM + n]);
        } else {
            int u = t - X_DIM * H_DIM;
            int y = u >> 8, k = u & 255;           // W2t[y][k] = W2[k][y]
            W2t[u] = f2bf(W2[k * Y_DIM + y]);
        }
    } else {
        __shared__ int h[NB];
        int j = b - NORM_BLOCKS - CONV_BLOCKS;     // chunk id 0..195
        int t = threadIdx.x;
        for (int i = t; i < NB; i += 256) h[i] = 0;
        __syncthreads();
        int base = j * CHUNK;
        #pragma unroll
        for (int k = 0; k < CHUNK / 256; k++) {
            int e = base + t + k * 256;
            if (e < N_EDGES) atomicAdd(&h[rows[e] >> BUCKET_SHIFT], 1);
        }
        __syncthreads();
        for (int i = t; i < NB; i += 256) gpartial[j * NB + i] = h[i];
    }
}

// ---------------------------------------------------------------------------
// Bucketize (scan folded in, verified R3): each of the 196 chunk-blocks
// redundantly reduces gpartial (306 KB, L2-hot) to get bucket totals + its
// own chunk prefix -> deterministic global write base, NO atomics, no scan
// kernel. Block 0 also emits bucket_base + sentinels.
// Edge payload: word0 = col(16) | lrow(7) | bucket(9), word1 = fp32 val.
// ---------------------------------------------------------------------------
__global__ __launch_bounds__(512) void bucketize_kernel(
    const int* __restrict__ rows, const int* __restrict__ cols,
    const float* __restrict__ vals, const int* __restrict__ gpartial,
    int2* __restrict__ edges, int* __restrict__ bucket_base,
    int* __restrict__ rowptr) {
    __shared__ int sc[512];            // scan scratch
    __shared__ int ob[512];            // chunk-local exclusive bucket offsets
    __shared__ int gw[NB];             // global write base for this chunk
    __shared__ int cur[NB];            // placement cursors
    __shared__ int2 buf[CHUNK];        // 32 KB
    int t = threadIdx.x;
    int j = blockIdx.x;
    int base = j * CHUNK;
    int M = N_EDGES - base; if (M > CHUNK) M = CHUNK;

    // totals over all chunks + prefix over chunks < j, for bucket t
    int total = 0, pre = 0, cnt = 0;
    if (t < NB) {
        for (int jj = 0; jj < NCHUNK; jj++) {
            int v = gpartial[jj * NB + t];
            total += v;
            pre += (jj < j) ? v : 0;
        }
        cnt = gpartial[j * NB + t];
    }
    // scan 1: exclusive scan of bucket totals -> bucket bases
    sc[t] = total;
    __syncthreads();
    #pragma unroll
    for (int off = 1; off < 512; off <<= 1) {
        int u = (t >= off) ? sc[t - off] : 0;
        __syncthreads();
        sc[t] += u;
        __syncthreads();
    }
    int bexcl = sc[t] - total;
    if (t < NB) { gw[t] = bexcl + pre; cur[t] = 0; }
    if (j == 0) {
        if (t < NB) bucket_base[t] = bexcl;
        if (t == 0) { bucket_base[NB] = N_EDGES; rowptr[N_NODES] = N_EDGES; }
    }
    // scan 2: chunk-local exclusive offsets
    sc[t] = cnt;
    __syncthreads();
    #pragma unroll
    for (int off = 1; off < 512; off <<= 1) {
        int u = (t >= off) ? sc[t - off] : 0;
        __syncthreads();
        sc[t] += u;
        __syncthreads();
    }
    ob[t] = sc[t] - cnt;
    __syncthreads();

    #pragma unroll
    for (int k = 0; k < CHUNK / 512; k++) {
        int e = base + t + k * 512;
        if (e < N_EDGES) {
            int r = rows[e];
            int bb = r >> BUCKET_SHIFT;
            int p = ob[bb] + atomicAdd(&cur[bb], 1);
            buf[p] = make_int2(cols[e] | ((r & 127) << 16) | (bb << 23),
                               __float_as_int(vals[e]));
        }
    }
    __syncthreads();
    for (int i = t; i < M; i += 512) {
        int2 e = buf[i];
        int bb = (int)((uint32)e.x >> 23);
        edges[gw[bb] + (i - ob[bb])] = e;
    }
}

// ---------------------------------------------------------------------------
// Bucket sort: per-bucket LDS counting sort by local row, in place; ALSO
// emits rowptr for its 128 rows. Global-scratch fallback if bucket > CAP_B
// (scratch aliases the hw region, which is dead at this point).
// ---------------------------------------------------------------------------
__global__ __launch_bounds__(256) void bucket_sort_kernel(
    const int* __restrict__ bucket_base, int2* __restrict__ edges,
    int2* __restrict__ scratch, int* __restrict__ rowptr) {
    __shared__ int2 buf[CAP_B];   // 20.5 KB
    __shared__ int2 buf2[CAP_B];  // 20.5 KB
    __shared__ int h[128], o[128], c[128];
    int b = blockIdx.x, t = threadIdx.x;
    int base = bucket_base[b];
    int cnt = bucket_base[b + 1] - base;
    bool fits = (cnt <= CAP_B);
    if (t < 128) h[t] = 0;
    __syncthreads();
    for (int i = t; i < cnt; i += 256) {
        int2 e = edges[base + i];
        if (fits) buf[i] = e; else scratch[base + i] = e;
        atomicAdd(&h[(e.x >> 16) & 127], 1);
    }
    __syncthreads();
    int valh = (t < 128) ? h[t] : 0;
    #pragma unroll
    for (int off = 1; off < 128; off <<= 1) {
        int u = (t >= off && t < 128) ? h[t - off] : 0;
        __syncthreads();
        if (t < 128) h[t] += u;
        __syncthreads();
    }
    if (t < 128) {
        o[t] = h[t] - valh;
        c[t] = 0;
        int i = (b << BUCKET_SHIFT) + t;
        if (i < N_NODES) rowptr[i] = base + h[t] - valh;
    }
    __syncthreads();
    for (int i = t; i < cnt; i += 256) {
        int2 e = fits ? buf[i] : scratch[base + i];
        int lr = (e.x >> 16) & 127;
        int p = o[lr] + atomicAdd(&c[lr], 1);
        if (fits) buf2[p] = e; else edges[base + p] = e;
    }
    __syncthreads();
    if (fits)
        for (int i = t; i < cnt; i += 256) edges[base + i] = buf2[i];
}

// ---------------------------------------------------------------------------
// Quad-row spmm accumulator (unchanged from R4): wave = 4 groups of 16
// lanes; group g processes its own row, lane owns dims g16*8..g16*8+7 via
// uint4 (= 8 bf16, 16 B). 8-wide edge unroll: 8 independent 16 B gathers in
// flight per group. start/end per-lane (uniform within each 16-lane group).
// ---------------------------------------------------------------------------
__device__ __forceinline__ void spmm_row4(const uint4* __restrict__ feat4,
                                          const int2* __restrict__ edges,
                                          int start, int end, int lane,
                                          float A[8]) {
    const int g16 = lane & 15;    // lane-in-group
    const int bsrc = lane & 48;   // shfl source base for my group
    int cur = start;
    while (__any(cur < end)) {
        int n = end - cur;
        n = n < 0 ? 0 : (n > 16 ? 16 : n);
        int2 ev = make_int2(0, 0);
        if (g16 < n) ev = edges[cur + g16];
        int c = ev.x & 0xFFFF;
        float v = __int_as_float(ev.y);
        int n0 = __shfl(n, 0, 64), n1 = __shfl(n, 16, 64);
        int n2 = __shfl(n, 32, 64), n3 = __shfl(n, 48, 64);
        int nm = max(max(n0, n1), max(n2, n3));
        int jm = (nm + 7) & ~7;
        for (int j = 0; j < jm; j += 8) {
            uint4 f[8];
            float vv[8];
            #pragma unroll
            for (int u = 0; u < 8; u++) {
                int cc = __shfl(c, bsrc + j + u, 64);
                vv[u] = __shfl(v, bsrc + j + u, 64);
                f[u] = feat4[(size_t)cc * 16 + g16];
            }
            #pragma unroll
            for (int u = 0; u < 8; u++) {
                A[0] += vv[u] * bf_lo(f[u].x); A[1] += vv[u] * bf_hi(f[u].x);
                A[2] += vv[u] * bf_lo(f[u].y); A[3] += vv[u] * bf_hi(f[u].y);
                A[4] += vv[u] * bf_lo(f[u].z); A[5] += vv[u] * bf_hi(f[u].z);
                A[6] += vv[u] * bf_lo(f[u].w); A[7] += vv[u] * bf_hi(f[u].w);
            }
        }
        cur += n;
    }
}

// ---------------------------------------------------------------------------
// spmm1: agg = A @ x-hat (bf16 out). Pure gather, ZERO LDS, VGPR forced
// <= 64 via launch_bounds(256,8) -> up to 32 waves/CU (vs 24 LDS-capped in
// the old fused kernel). Occupancy A/B vs spmm_out (identical gather,
// default bounds). Grid exact: 3125 blocks x 4 waves x 4 rows = 50000.
// ---------------------------------------------------------------------------
__global__ __launch_bounds__(256, 8) void spmm1_kernel(
    const uint32* __restrict__ xb, const int* __restrict__ rowptr,
    const int2* __restrict__ edges, uint32* __restrict__ agg) {
    int w = (blockIdx.x * blockDim.x + threadIdx.x) >> 6;
    int lane = threadIdx.x & 63;
    int quad = lane >> 4, g16 = lane & 15;
    int row = w * 4 + quad;  // always < N_NODES (exact grid)
    int s = rowptr[row], e = rowptr[row + 1];
    float A[8] = {0.f, 0.f, 0.f, 0.f, 0.f, 0.f, 0.f, 0.f};
    spmm_row4((const uint4*)xb, edges, s, e, lane, A);
    uint4 pk;
    pk.x = (uint32)f2bf(A[0]) | ((uint32)f2bf(A[1]) << 16);
    pk.y = (uint32)f2bf(A[2]) | ((uint32)f2bf(A[3]) << 16);
    pk.z = (uint32)f2bf(A[4]) | ((uint32)f2bf(A[5]) << 16);
    pk.w = (uint32)f2bf(A[6]) | ((uint32)f2bf(A[7]) << 16);
    ((uint4*)agg)[(size_t)row * 16 + g16] = pk;
}

// ---------------------------------------------------------------------------
// GEMM kernel per 64-row tile (512 thr, 8 waves): hw = relu(agg@W1+b1)@W2.
// A-fragments read straight from global agg (L2/L3-hot, 16 KB/block tile);
// LDS = h_s only (33.8 KB). One barrier. Same MFMA layout as the old fused
// phases 1-2.
// ---------------------------------------------------------------------------
__global__ __launch_bounds__(512, 4) void gemm_kernel(
    const ushort16* __restrict__ agg, const ushort16* __restrict__ W1t,
    const ushort16* __restrict__ W2t, const float* __restrict__ b1,
    ushort16* __restrict__ hw) {
    __shared__ ushort16 h_s[64 * 264];  // 33.8 KB
    const int tx = threadIdx.x;
    const int wave = tx >> 6, lane = tx & 63;
    const int quad = lane >> 4, l16 = lane & 15;
    const int row0 = blockIdx.x * 64;

    // stage-1 B fragments: wave owns h-cols [wave*32, wave*32+32)
    short8 bfr1[2][4];  // [ct][kk]
    #pragma unroll
    for (int ct = 0; ct < 2; ct++)
        #pragma unroll
        for (int kk = 0; kk < 4; kk++)
            bfr1[ct][kk] = *(const short8*)
                &W1t[(wave * 32 + ct * 16 + l16) * 128 + kk * 32 + quad * 8];

    // Phase 1: h = relu(A @ W1 + b1), A-frags from global agg
    floatx4 acc1[4][2];  // [rs][ct]
    #pragma unroll
    for (int rs = 0; rs < 4; rs++)
        #pragma unroll
        for (int ct = 0; ct < 2; ct++)
            #pragma unroll
            for (int j = 0; j < 4; j++) acc1[rs][ct][j] = 0.f;
    #pragma unroll
    for (int kk = 0; kk < 4; kk++) {
        #pragma unroll
        for (int rs = 0; rs < 4; rs++) {
            int row = row0 + rs * 16 + l16;
            short8 af = {};
            if (row < N_NODES)
                af = *(const short8*)&agg[(size_t)row * 128 + kk * 32 + quad * 8];
            #pragma unroll
            for (int ct = 0; ct < 2; ct++)
                acc1[rs][ct] = __builtin_amdgcn_mfma_f32_16x16x32_bf16(
                    af, bfr1[ct][kk], acc1[rs][ct], 0, 0, 0);
        }
    }
    float bv[2];
    #pragma unroll
    for (int ct = 0; ct < 2; ct++) bv[ct] = b1[wave * 32 + ct * 16 + l16];
    #pragma unroll
    for (int rs = 0; rs < 4; rs++)
        #pragma unroll
        for (int ct = 0; ct < 2; ct++)
            #pragma unroll
            for (int reg = 0; reg < 4; reg++) {
                float v = acc1[rs][ct][reg] + bv[ct];
                v = v > 0.f ? v : 0.f;
                h_s[(rs * 16 + quad * 4 + reg) * 264 + wave * 32 + ct * 16 + l16] = f2bf(v);
            }

    // stage-2 B fragments: wave owns hw-cols [wave*16, wave*16+16)
    short8 bfr2[8];
    #pragma unroll
    for (int kk = 0; kk < 8; kk++)
        bfr2[kk] = *(const short8*)
            &W2t[(wave * 16 + l16) * 256 + kk * 32 + quad * 8];
    __syncthreads();

    // Phase 2: hw = h @ W2
    floatx4 acc2[4];
    #pragma unroll
    for (int rs = 0; rs < 4; rs++)
        #pragma unroll
        for (int j = 0; j < 4; j++) acc2[rs][j] = 0.f;
    #pragma unroll
    for (int kk = 0; kk < 8; kk++) {
        #pragma unroll
        for (int rs = 0; rs < 4; rs++) {
            short8 af = *(const short8*)&h_s[(rs * 16 + l16) * 264 + kk * 32 + quad * 8];
            acc2[rs] = __builtin_amdgcn_mfma_f32_16x16x32_bf16(
                af, bfr2[kk], acc2[rs], 0, 0, 0);
        }
    }
    #pragma unroll
    for (int rs = 0; rs < 4; rs++)
        #pragma unroll
        for (int reg = 0; reg < 4; reg++) {
            int row = row0 + rs * 16 + quad * 4 + reg;
            if (row < N_NODES)
                hw[(size_t)row * 128 + wave * 16 + l16] = f2bf(acc2[rs][reg]);
        }
}

// ---------------------------------------------------------------------------
// Final spmm (unchanged from R4): out = A @ hw + b2 (fp32 out). One wave
// per 4 rows (quad-row). Grid exact: 3125 blocks x 4 waves x 4 rows = 50000.
// ---------------------------------------------------------------------------
__global__ __launch_bounds__(256) void spmm_out_kernel(
    const uint32* __restrict__ feat, const int* __restrict__ rowptr,
    const int2* __restrict__ edges, const float* __restrict__ bias,
    float* __restrict__ out) {
    int w = (blockIdx.x * blockDim.x + threadIdx.x) >> 6;
    int lane = threadIdx.x & 63;
    int quad = lane >> 4, g16 = lane & 15;
    int row = w * 4 + quad;  // always < N_NODES (exact grid)
    int s = rowptr[row], e = rowptr[row + 1];
    float A[8] = {0.f, 0.f, 0.f, 0.f, 0.f, 0.f, 0.f, 0.f};
    spmm_row4((const uint4*)feat, edges, s, e, lane, A);
    float4 b0 = ((const float4*)bias)[g16 * 2];
    float4 b1 = ((const float4*)bias)[g16 * 2 + 1];
    ((float4*)out)[(size_t)row * 32 + g16 * 2] =
        make_float4(A[0] + b0.x, A[1] + b0.y, A[2] + b0.z, A[3] + b0.w);
    ((float4*)out)[(size_t)row * 32 + g16 * 2 + 1] =
        make_float4(A[4] + b1.x, A[5] + b1.y, A[6] + b1.z, A[7] + b1.w);
}

extern "C" void kernel_launch(void* const* d_in, const int* in_sizes, int n_in,
                              void* d_out, int out_size, void* d_ws, size_t ws_size,
                              hipStream_t stream) {
    const float* x = (const float*)d_in[0];
    const float* adj_vals = (const float*)d_in[1];
    const int* adj_row = (const int*)d_in[2];
    const int* adj_col = (const int*)d_in[3];
    const float* W1 = (const float*)d_in[4];
    const float* b1 = (const float*)d_in[5];
    const float* W2 = (const float*)d_in[6];
    const float* b2 = (const float*)d_in[7];
    float* out = (float*)d_out;

    // Workspace layout (~45.5 MB). Liveness-based aliasing:
    //   scratch (sort fallback) aliases hw  (hw written only later by gemm)
    //   agg overlays the old scratch region (written only after sort)
    char* ws = (char*)d_ws;
    uint32*   xb       = (uint32*)  (ws + 0);            // 12.8 MB (bf16 x-norm)
    ushort16* hw       = (ushort16*)(ws + 12800000);     // 12.8 MB (bf16)
    int2*     scratch  = (int2*)    (ws + 12800000);     //  alias: sort fallback
    int2*     edges    = (int2*)    (ws + 25600000);     //  6.4 MB
    ushort16* agg      = (ushort16*)(ws + 32000000);     // 12.8 MB (bf16 A@x-hat)
    int*      gpartial = (int*)     (ws + 44800000);     //  306 KB
    int*      rowptr   = (int*)     (ws + 45106560);     //  200 KB
    int*      bbase    = (int*)     (ws + 45306624);     //  1.6 KB
    ushort16* W1t      = (ushort16*)(ws + 45308224);     //   64 KB
    ushort16* W2t      = (ushort16*)(ws + 45373760);     //   64 KB

    // 1. prep: x-hat bf16 + transposed bf16 weights + per-chunk bucket hists
    hipLaunchKernelGGL(prep_kernel, dim3(NORM_BLOCKS + CONV_BLOCKS + NCHUNK),
                       dim3(256), 0, stream, x, xb, W1, W2, W1t, W2t,
                       adj_row, gpartial);

    // 2. bucketize (scan folded in, atomic-free deterministic placement)
    hipLaunchKernelGGL(bucketize_kernel, dim3(NCHUNK), dim3(512),
                       0, stream, adj_row, adj_col, adj_vals, gpartial,
                       edges, bbase, rowptr);

    // 3. per-bucket sort (emits rowptr)
    hipLaunchKernelGGL(bucket_sort_kernel, dim3(NB), dim3(256),
                       0, stream, bbase, edges, scratch, rowptr);

    // 4. agg = A @ x-hat   [pure gather, zero LDS, max occupancy]
    hipLaunchKernelGGL(spmm1_kernel, dim3(N_NODES / 16), dim3(256),
                       0, stream, xb, rowptr, edges, (uint32*)agg);

    // 5. hw = relu(agg @ W1 + b1) @ W2   [MFMA GEMMs]
    hipLaunchKernelGGL(gemm_kernel, dim3((N_NODES + 63) / 64), dim3(512),
                       0, stream, agg, W1t, W2t, b1, hw);

    // 6. out = A @ hw + b2
    hipLaunchKernelGGL(spmm_out_kernel, dim3(N_NODES / 16), dim3(256),
                       0, stream, (const uint32*)hw, rowptr, edges, b2, out);
}

// Round 6
// 222.016 us; speedup vs baseline: 1.3543x; 1.3543x over previous
//
#include <hip/hip_runtime.h>

// Problem constants (fixed by the reference).
#define N_NODES 50000
#define N_EDGES 800000
#define X_DIM 128
#define H_DIM 256
#define Y_DIM 128

typedef unsigned int uint32;
typedef unsigned short ushort16;
typedef __attribute__((ext_vector_type(8))) short short8;
typedef __attribute__((ext_vector_type(4))) float floatx4;

// bf16 helpers (round-to-nearest-even)
__device__ inline ushort16 f2bf(float f) {
    uint32 u = __float_as_uint(f);
    return (ushort16)((u + 0x7FFFu + ((u >> 16) & 1u)) >> 16);
}
__device__ inline float bf_lo(uint32 u) { return __uint_as_float(u << 16); }
__device__ inline float bf_hi(uint32 u) { return __uint_as_float(u & 0xFFFF0000u); }

// Bucket geometry: 391 buckets of 128 rows; 196 chunks of 4096 edges.
#define BUCKET_SHIFT 7
#define NB 391              // ceil(50000/128)
#define CHUNK 4096
#define NCHUNK 196          // ceil(800000/4096)
#define CAP_B 2560          // LDS capacity per bucket (mean 2046)

#define NORM_BLOCKS 12500   // N_NODES*64/256
#define CONV_BLOCKS 256     // 65536/256

// ---------------------------------------------------------------------------
// Prep (fused): row-normalize x -> bf16; transpose-convert W1,W2 to bf16;
// per-chunk bucket histograms -> gpartial[chunk][bucket] (no global atomics).
// ---------------------------------------------------------------------------
__global__ __launch_bounds__(256) void prep_kernel(
    const float* __restrict__ x, uint32* __restrict__ xb,
    const float* __restrict__ W1, const float* __restrict__ W2,
    ushort16* __restrict__ W1t, ushort16* __restrict__ W2t,
    const int* __restrict__ rows, int* __restrict__ gpartial) {
    int b = blockIdx.x;
    if (b < NORM_BLOCKS) {
        int row = (b * 256 + threadIdx.x) >> 6;  // exact: 12500*4 = 50000 rows
        int lane = threadIdx.x & 63;
        float2 v = ((const float2*)x)[(size_t)row * 64 + lane];
        float s = v.x + v.y;
        #pragma unroll
        for (int off = 32; off > 0; off >>= 1) s += __shfl_xor(s, off, 64);
        float inv = 1.0f / (s + 1e-4f);
        uint32 lo = (uint32)f2bf(v.x * inv);
        uint32 hi = (uint32)f2bf(v.y * inv);
        xb[(size_t)row * 64 + lane] = lo | (hi << 16);
    } else if (b < NORM_BLOCKS + CONV_BLOCKS) {
        int t = (b - NORM_BLOCKS) * 256 + threadIdx.x;  // 0..65535
        if (t < X_DIM * H_DIM) {
            int n = t >> 7, k = t & 127;           // W1t[n][k] = W1[k][n]
            W1t[t] = f2bf(W1[k * H_DIM + n]);
        } else {
            int u = t - X_DIM * H_DIM;
            int y = u >> 8, k = u & 255;           // W2t[y][k] = W2[k][y]
            W2t[u] = f2bf(W2[k * Y_DIM + y]);
        }
    } else {
        __shared__ int h[NB];
        int j = b - NORM_BLOCKS - CONV_BLOCKS;     // chunk id 0..195
        int t = threadIdx.x;
        for (int i = t; i < NB; i += 256) h[i] = 0;
        __syncthreads();
        int base = j * CHUNK;
        #pragma unroll
        for (int k = 0; k < CHUNK / 256; k++) {
            int e = base + t + k * 256;
            if (e < N_EDGES) atomicAdd(&h[rows[e] >> BUCKET_SHIFT], 1);
        }
        __syncthreads();
        for (int i = t; i < NB; i += 256) gpartial[j * NB + i] = h[i];
    }
}

// ---------------------------------------------------------------------------
// Bucketize (scan folded in, verified R3): each of the 196 chunk-blocks
// redundantly reduces gpartial (306 KB, L2-hot) to get bucket totals + its
// own chunk prefix -> deterministic global write base, NO atomics, no scan
// kernel. Block 0 also emits bucket_base + sentinels.
// Edge payload: word0 = col(16) | lrow(7) | bucket(9), word1 = fp32 val.
// ---------------------------------------------------------------------------
__global__ __launch_bounds__(512) void bucketize_kernel(
    const int* __restrict__ rows, const int* __restrict__ cols,
    const float* __restrict__ vals, const int* __restrict__ gpartial,
    int2* __restrict__ edges, int* __restrict__ bucket_base,
    int* __restrict__ rowptr) {
    __shared__ int sc[512];            // scan scratch
    __shared__ int ob[512];            // chunk-local exclusive bucket offsets
    __shared__ int gw[NB];             // global write base for this chunk
    __shared__ int cur[NB];            // placement cursors
    __shared__ int2 buf[CHUNK];        // 32 KB
    int t = threadIdx.x;
    int j = blockIdx.x;
    int base = j * CHUNK;
    int M = N_EDGES - base; if (M > CHUNK) M = CHUNK;

    // totals over all chunks + prefix over chunks < j, for bucket t
    int total = 0, pre = 0, cnt = 0;
    if (t < NB) {
        for (int jj = 0; jj < NCHUNK; jj++) {
            int v = gpartial[jj * NB + t];
            total += v;
            pre += (jj < j) ? v : 0;
        }
        cnt = gpartial[j * NB + t];
    }
    // scan 1: exclusive scan of bucket totals -> bucket bases
    sc[t] = total;
    __syncthreads();
    #pragma unroll
    for (int off = 1; off < 512; off <<= 1) {
        int u = (t >= off) ? sc[t - off] : 0;
        __syncthreads();
        sc[t] += u;
        __syncthreads();
    }
    int bexcl = sc[t] - total;
    if (t < NB) { gw[t] = bexcl + pre; cur[t] = 0; }
    if (j == 0) {
        if (t < NB) bucket_base[t] = bexcl;
        if (t == 0) { bucket_base[NB] = N_EDGES; rowptr[N_NODES] = N_EDGES; }
    }
    // scan 2: chunk-local exclusive offsets
    sc[t] = cnt;
    __syncthreads();
    #pragma unroll
    for (int off = 1; off < 512; off <<= 1) {
        int u = (t >= off) ? sc[t - off] : 0;
        __syncthreads();
        sc[t] += u;
        __syncthreads();
    }
    ob[t] = sc[t] - cnt;
    __syncthreads();

    #pragma unroll
    for (int k = 0; k < CHUNK / 512; k++) {
        int e = base + t + k * 512;
        if (e < N_EDGES) {
            int r = rows[e];
            int bb = r >> BUCKET_SHIFT;
            int p = ob[bb] + atomicAdd(&cur[bb], 1);
            buf[p] = make_int2(cols[e] | ((r & 127) << 16) | (bb << 23),
                               __float_as_int(vals[e]));
        }
    }
    __syncthreads();
    for (int i = t; i < M; i += 512) {
        int2 e = buf[i];
        int bb = (int)((uint32)e.x >> 23);
        edges[gw[bb] + (i - ob[bb])] = e;
    }
}

// ---------------------------------------------------------------------------
// Bucket sort: per-bucket LDS counting sort by local row, in place; ALSO
// emits rowptr for its 128 rows. Global-scratch fallback if bucket > CAP_B
// (scratch aliases the hw region, which is dead at this point).
// ---------------------------------------------------------------------------
__global__ __launch_bounds__(256) void bucket_sort_kernel(
    const int* __restrict__ bucket_base, int2* __restrict__ edges,
    int2* __restrict__ scratch, int* __restrict__ rowptr) {
    __shared__ int2 buf[CAP_B];   // 20.5 KB
    __shared__ int2 buf2[CAP_B];  // 20.5 KB
    __shared__ int h[128], o[128], c[128];
    int b = blockIdx.x, t = threadIdx.x;
    int base = bucket_base[b];
    int cnt = bucket_base[b + 1] - base;
    bool fits = (cnt <= CAP_B);
    if (t < 128) h[t] = 0;
    __syncthreads();
    for (int i = t; i < cnt; i += 256) {
        int2 e = edges[base + i];
        if (fits) buf[i] = e; else scratch[base + i] = e;
        atomicAdd(&h[(e.x >> 16) & 127], 1);
    }
    __syncthreads();
    int valh = (t < 128) ? h[t] : 0;
    #pragma unroll
    for (int off = 1; off < 128; off <<= 1) {
        int u = (t >= off && t < 128) ? h[t - off] : 0;
        __syncthreads();
        if (t < 128) h[t] += u;
        __syncthreads();
    }
    if (t < 128) {
        o[t] = h[t] - valh;
        c[t] = 0;
        int i = (b << BUCKET_SHIFT) + t;
        if (i < N_NODES) rowptr[i] = base + h[t] - valh;
    }
    __syncthreads();
    for (int i = t; i < cnt; i += 256) {
        int2 e = fits ? buf[i] : scratch[base + i];
        int lr = (e.x >> 16) & 127;
        int p = o[lr] + atomicAdd(&c[lr], 1);
        if (fits) buf2[p] = e; else edges[base + p] = e;
    }
    __syncthreads();
    if (fits)
        for (int i = t; i < cnt; i += 256) edges[base + i] = buf2[i];
}

// ---------------------------------------------------------------------------
// Quad-row spmm accumulator (unchanged from R4): wave = 4 groups of 16
// lanes; group g processes its own row, lane owns dims g16*8..g16*8+7 via
// uint4 (= 8 bf16, 16 B). 8-wide edge unroll: 8 independent 16 B gathers in
// flight per group. start/end per-lane (uniform within each 16-lane group).
// ---------------------------------------------------------------------------
__device__ __forceinline__ void spmm_row4(const uint4* __restrict__ feat4,
                                          const int2* __restrict__ edges,
                                          int start, int end, int lane,
                                          float A[8]) {
    const int g16 = lane & 15;    // lane-in-group
    const int bsrc = lane & 48;   // shfl source base for my group
    int cur = start;
    while (__any(cur < end)) {
        int n = end - cur;
        n = n < 0 ? 0 : (n > 16 ? 16 : n);
        int2 ev = make_int2(0, 0);
        if (g16 < n) ev = edges[cur + g16];
        int c = ev.x & 0xFFFF;
        float v = __int_as_float(ev.y);
        int n0 = __shfl(n, 0, 64), n1 = __shfl(n, 16, 64);
        int n2 = __shfl(n, 32, 64), n3 = __shfl(n, 48, 64);
        int nm = max(max(n0, n1), max(n2, n3));
        int jm = (nm + 7) & ~7;
        for (int j = 0; j < jm; j += 8) {
            uint4 f[8];
            float vv[8];
            #pragma unroll
            for (int u = 0; u < 8; u++) {
                int cc = __shfl(c, bsrc + j + u, 64);
                vv[u] = __shfl(v, bsrc + j + u, 64);
                f[u] = feat4[(size_t)cc * 16 + g16];
            }
            #pragma unroll
            for (int u = 0; u < 8; u++) {
                A[0] += vv[u] * bf_lo(f[u].x); A[1] += vv[u] * bf_hi(f[u].x);
                A[2] += vv[u] * bf_lo(f[u].y); A[3] += vv[u] * bf_hi(f[u].y);
                A[4] += vv[u] * bf_lo(f[u].z); A[5] += vv[u] * bf_hi(f[u].z);
                A[6] += vv[u] * bf_lo(f[u].w); A[7] += vv[u] * bf_hi(f[u].w);
            }
        }
        cur += n;
    }
}

// ---------------------------------------------------------------------------
// spmm1: agg = A @ x-hat (bf16 out). Pure gather, ZERO LDS.
// launch_bounds(256, 4): 128-VGPR cap -- the same cap under which this
// gather compiled spill-free to 60 VGPR inside the R4 fused kernel, so the
// HW can still co-resident 8 waves/SIMD. (R5's (256,8) forced 32 VGPR ->
// 470 MB of scratch spill traffic; that experiment showed the kernel runs
// HBM-BW-bound at 4.6 TB/s once occupancy is high.)
// Grid exact: 3125 blocks x 4 waves x 4 rows = 50000.
// ---------------------------------------------------------------------------
__global__ __launch_bounds__(256, 4) void spmm1_kernel(
    const uint32* __restrict__ xb, const int* __restrict__ rowptr,
    const int2* __restrict__ edges, uint32* __restrict__ agg) {
    int w = (blockIdx.x * blockDim.x + threadIdx.x) >> 6;
    int lane = threadIdx.x & 63;
    int quad = lane >> 4, g16 = lane & 15;
    int row = w * 4 + quad;  // always < N_NODES (exact grid)
    int s = rowptr[row], e = rowptr[row + 1];
    float A[8] = {0.f, 0.f, 0.f, 0.f, 0.f, 0.f, 0.f, 0.f};
    spmm_row4((const uint4*)xb, edges, s, e, lane, A);
    uint4 pk;
    pk.x = (uint32)f2bf(A[0]) | ((uint32)f2bf(A[1]) << 16);
    pk.y = (uint32)f2bf(A[2]) | ((uint32)f2bf(A[3]) << 16);
    pk.z = (uint32)f2bf(A[4]) | ((uint32)f2bf(A[5]) << 16);
    pk.w = (uint32)f2bf(A[6]) | ((uint32)f2bf(A[7]) << 16);
    ((uint4*)agg)[(size_t)row * 16 + g16] = pk;
}

// ---------------------------------------------------------------------------
// GEMM kernel per 64-row tile (512 thr, 8 waves): hw = relu(agg@W1+b1)@W2.
// A-fragments read straight from global agg (L2/L3-hot, 16 KB/block tile);
// LDS = h_s only (33.8 KB). One barrier. Same MFMA layout as the old fused
// phases 1-2.
// ---------------------------------------------------------------------------
__global__ __launch_bounds__(512, 4) void gemm_kernel(
    const ushort16* __restrict__ agg, const ushort16* __restrict__ W1t,
    const ushort16* __restrict__ W2t, const float* __restrict__ b1,
    ushort16* __restrict__ hw) {
    __shared__ ushort16 h_s[64 * 264];  // 33.8 KB
    const int tx = threadIdx.x;
    const int wave = tx >> 6, lane = tx & 63;
    const int quad = lane >> 4, l16 = lane & 15;
    const int row0 = blockIdx.x * 64;

    // stage-1 B fragments: wave owns h-cols [wave*32, wave*32+32)
    short8 bfr1[2][4];  // [ct][kk]
    #pragma unroll
    for (int ct = 0; ct < 2; ct++)
        #pragma unroll
        for (int kk = 0; kk < 4; kk++)
            bfr1[ct][kk] = *(const short8*)
                &W1t[(wave * 32 + ct * 16 + l16) * 128 + kk * 32 + quad * 8];

    // Phase 1: h = relu(A @ W1 + b1), A-frags from global agg
    floatx4 acc1[4][2];  // [rs][ct]
    #pragma unroll
    for (int rs = 0; rs < 4; rs++)
        #pragma unroll
        for (int ct = 0; ct < 2; ct++)
            #pragma unroll
            for (int j = 0; j < 4; j++) acc1[rs][ct][j] = 0.f;
    #pragma unroll
    for (int kk = 0; kk < 4; kk++) {
        #pragma unroll
        for (int rs = 0; rs < 4; rs++) {
            int row = row0 + rs * 16 + l16;
            short8 af = {};
            if (row < N_NODES)
                af = *(const short8*)&agg[(size_t)row * 128 + kk * 32 + quad * 8];
            #pragma unroll
            for (int ct = 0; ct < 2; ct++)
                acc1[rs][ct] = __builtin_amdgcn_mfma_f32_16x16x32_bf16(
                    af, bfr1[ct][kk], acc1[rs][ct], 0, 0, 0);
        }
    }
    float bv[2];
    #pragma unroll
    for (int ct = 0; ct < 2; ct++) bv[ct] = b1[wave * 32 + ct * 16 + l16];
    #pragma unroll
    for (int rs = 0; rs < 4; rs++)
        #pragma unroll
        for (int ct = 0; ct < 2; ct++)
            #pragma unroll
            for (int reg = 0; reg < 4; reg++) {
                float v = acc1[rs][ct][reg] + bv[ct];
                v = v > 0.f ? v : 0.f;
                h_s[(rs * 16 + quad * 4 + reg) * 264 + wave * 32 + ct * 16 + l16] = f2bf(v);
            }

    // stage-2 B fragments: wave owns hw-cols [wave*16, wave*16+16)
    short8 bfr2[8];
    #pragma unroll
    for (int kk = 0; kk < 8; kk++)
        bfr2[kk] = *(const short8*)
            &W2t[(wave * 16 + l16) * 256 + kk * 32 + quad * 8];
    __syncthreads();

    // Phase 2: hw = h @ W2
    floatx4 acc2[4];
    #pragma unroll
    for (int rs = 0; rs < 4; rs++)
        #pragma unroll
        for (int j = 0; j < 4; j++) acc2[rs][j] = 0.f;
    #pragma unroll
    for (int kk = 0; kk < 8; kk++) {
        #pragma unroll
        for (int rs = 0; rs < 4; rs++) {
            short8 af = *(const short8*)&h_s[(rs * 16 + l16) * 264 + kk * 32 + quad * 8];
            acc2[rs] = __builtin_amdgcn_mfma_f32_16x16x32_bf16(
                af, bfr2[kk], acc2[rs], 0, 0, 0);
        }
    }
    #pragma unroll
    for (int rs = 0; rs < 4; rs++)
        #pragma unroll
        for (int reg = 0; reg < 4; reg++) {
            int row = row0 + rs * 16 + quad * 4 + reg;
            if (row < N_NODES)
                hw[(size_t)row * 128 + wave * 16 + l16] = f2bf(acc2[rs][reg]);
        }
}

// ---------------------------------------------------------------------------
// Final spmm (unchanged from R4): out = A @ hw + b2 (fp32 out). One wave
// per 4 rows (quad-row). Grid exact: 3125 blocks x 4 waves x 4 rows = 50000.
// ---------------------------------------------------------------------------
__global__ __launch_bounds__(256, 4) void spmm_out_kernel(
    const uint32* __restrict__ feat, const int* __restrict__ rowptr,
    const int2* __restrict__ edges, const float* __restrict__ bias,
    float* __restrict__ out) {
    int w = (blockIdx.x * blockDim.x + threadIdx.x) >> 6;
    int lane = threadIdx.x & 63;
    int quad = lane >> 4, g16 = lane & 15;
    int row = w * 4 + quad;  // always < N_NODES (exact grid)
    int s = rowptr[row], e = rowptr[row + 1];
    float A[8] = {0.f, 0.f, 0.f, 0.f, 0.f, 0.f, 0.f, 0.f};
    spmm_row4((const uint4*)feat, edges, s, e, lane, A);
    float4 b0 = ((const float4*)bias)[g16 * 2];
    float4 b1 = ((const float4*)bias)[g16 * 2 + 1];
    ((float4*)out)[(size_t)row * 32 + g16 * 2] =
        make_float4(A[0] + b0.x, A[1] + b0.y, A[2] + b0.z, A[3] + b0.w);
    ((float4*)out)[(size_t)row * 32 + g16 * 2 + 1] =
        make_float4(A[4] + b1.x, A[5] + b1.y, A[6] + b1.z, A[7] + b1.w);
}

extern "C" void kernel_launch(void* const* d_in, const int* in_sizes, int n_in,
                              void* d_out, int out_size, void* d_ws, size_t ws_size,
                              hipStream_t stream) {
    const float* x = (const float*)d_in[0];
    const float* adj_vals = (const float*)d_in[1];
    const int* adj_row = (const int*)d_in[2];
    const int* adj_col = (const int*)d_in[3];
    const float* W1 = (const float*)d_in[4];
    const float* b1 = (const float*)d_in[5];
    const float* W2 = (const float*)d_in[6];
    const float* b2 = (const float*)d_in[7];
    float* out = (float*)d_out;

    // Workspace layout (~45.5 MB). Liveness-based aliasing:
    //   scratch (sort fallback) aliases hw  (hw written only later by gemm)
    //   agg overlays the old scratch region (written only after sort)
    char* ws = (char*)d_ws;
    uint32*   xb       = (uint32*)  (ws + 0);            // 12.8 MB (bf16 x-norm)
    ushort16* hw       = (ushort16*)(ws + 12800000);     // 12.8 MB (bf16)
    int2*     scratch  = (int2*)    (ws + 12800000);     //  alias: sort fallback
    int2*     edges    = (int2*)    (ws + 25600000);     //  6.4 MB
    ushort16* agg      = (ushort16*)(ws + 32000000);     // 12.8 MB (bf16 A@x-hat)
    int*      gpartial = (int*)     (ws + 44800000);     //  306 KB
    int*      rowptr   = (int*)     (ws + 45106560);     //  200 KB
    int*      bbase    = (int*)     (ws + 45306624);     //  1.6 KB
    ushort16* W1t      = (ushort16*)(ws + 45308224);     //   64 KB
    ushort16* W2t      = (ushort16*)(ws + 45373760);     //   64 KB

    // 1. prep: x-hat bf16 + transposed bf16 weights + per-chunk bucket hists
    hipLaunchKernelGGL(prep_kernel, dim3(NORM_BLOCKS + CONV_BLOCKS + NCHUNK),
                       dim3(256), 0, stream, x, xb, W1, W2, W1t, W2t,
                       adj_row, gpartial);

    // 2. bucketize (scan folded in, atomic-free deterministic placement)
    hipLaunchKernelGGL(bucketize_kernel, dim3(NCHUNK), dim3(512),
                       0, stream, adj_row, adj_col, adj_vals, gpartial,
                       edges, bbase, rowptr);

    // 3. per-bucket sort (emits rowptr)
    hipLaunchKernelGGL(bucket_sort_kernel, dim3(NB), dim3(256),
                       0, stream, bbase, edges, scratch, rowptr);

    // 4. agg = A @ x-hat   [pure gather, zero LDS, high occupancy, no spill]
    hipLaunchKernelGGL(spmm1_kernel, dim3(N_NODES / 16), dim3(256),
                       0, stream, xb, rowptr, edges, (uint32*)agg);

    // 5. hw = relu(agg @ W1 + b1) @ W2   [MFMA GEMMs]
    hipLaunchKernelGGL(gemm_kernel, dim3((N_NODES + 63) / 64), dim3(512),
                       0, stream, agg, W1t, W2t, b1, hw);

    // 6. out = A @ hw + b2
    hipLaunchKernelGGL(spmm_out_kernel, dim3(N_NODES / 16), dim3(256),
                       0, stream, (const uint32*)hw, rowptr, edges, b2, out);
}

// Round 8
// 216.232 us; speedup vs baseline: 1.3905x; 1.0267x over previous
//
#include <hip/hip_runtime.h>

// Problem constants (fixed by the reference).
#define N_NODES 50000
#define N_EDGES 800000
#define X_DIM 128
#define H_DIM 256
#define Y_DIM 128

typedef unsigned int uint32;
typedef unsigned short ushort16;
typedef __attribute__((ext_vector_type(8))) short short8;
typedef __attribute__((ext_vector_type(4))) float floatx4;

// bf16 helpers (round-to-nearest-even)
__device__ inline ushort16 f2bf(float f) {
    uint32 u = __float_as_uint(f);
    return (ushort16)((u + 0x7FFFu + ((u >> 16) & 1u)) >> 16);
}
__device__ inline float bf_lo(uint32 u) { return __uint_as_float(u << 16); }
__device__ inline float bf_hi(uint32 u) { return __uint_as_float(u & 0xFFFF0000u); }

// int8 -> float byte extracts. Plain C form: LLVM AMDGPU pattern-matches
// uitofp(and(lshr(u,8k),255)) to v_cvt_f32_ubyte{0-3} (no builtin needed).
__device__ inline float ub0(uint32 u) { return (float)(u & 0xFFu); }
__device__ inline float ub1(uint32 u) { return (float)((u >> 8) & 0xFFu); }
__device__ inline float ub2(uint32 u) { return (float)((u >> 16) & 0xFFu); }
__device__ inline float ub3(uint32 u) { return (float)(u >> 24); }

// Bucket geometry: 391 buckets of 128 rows; 196 chunks of 4096 edges.
#define BUCKET_SHIFT 7
#define NB 391              // ceil(50000/128)
#define CHUNK 4096
#define NCHUNK 196          // ceil(800000/4096)
#define CAP_B 2560          // LDS capacity per bucket (mean 2046)

#define NORM_BLOCKS 12500   // N_NODES*64/256
#define CONV_BLOCKS 256     // 65536/256

// ---------------------------------------------------------------------------
// Prep (fused): row-normalize x -> int8 rows (q = round(x*127/rowmax)) +
// per-row fp32 scale = rowmax*inv/127 (so scale*q == x-hat to ~0.4%);
// transpose-convert W1,W2 to bf16; per-chunk bucket histograms.
// ---------------------------------------------------------------------------
__global__ __launch_bounds__(256) void prep_kernel(
    const float* __restrict__ x, unsigned short* __restrict__ xq,
    float* __restrict__ scales,
    const float* __restrict__ W1, const float* __restrict__ W2,
    ushort16* __restrict__ W1t, ushort16* __restrict__ W2t,
    const int* __restrict__ rows, int* __restrict__ gpartial) {
    int b = blockIdx.x;
    if (b < NORM_BLOCKS) {
        int row = (b * 256 + threadIdx.x) >> 6;  // exact: 12500*4 = 50000 rows
        int lane = threadIdx.x & 63;
        float2 v = ((const float2*)x)[(size_t)row * 64 + lane];
        float s = v.x + v.y;
        float m = fmaxf(v.x, v.y);
        #pragma unroll
        for (int off = 32; off > 0; off >>= 1) {
            s += __shfl_xor(s, off, 64);
            m = fmaxf(m, __shfl_xor(m, off, 64));
        }
        float inv = 1.0f / (s + 1e-4f);
        float rq = (m > 0.f) ? 127.f / m : 0.f;
        int q0 = (int)(v.x * rq + 0.5f);
        int q1 = (int)(v.y * rq + 0.5f);
        xq[(size_t)row * 64 + lane] = (unsigned short)(q0 | (q1 << 8));
        if (lane == 0) scales[row] = m * inv * (1.f / 127.f);
    } else if (b < NORM_BLOCKS + CONV_BLOCKS) {
        int t = (b - NORM_BLOCKS) * 256 + threadIdx.x;  // 0..65535
        if (t < X_DIM * H_DIM) {
            int n = t >> 7, k = t & 127;           // W1t[n][k] = W1[k][n]
            W1t[t] = f2bf(W1[k * H_DIM + n]);
        } else {
            int u = t - X_DIM * H_DIM;
            int y = u >> 8, k = u & 255;           // W2t[y][k] = W2[k][y]
            W2t[u] = f2bf(W2[k * Y_DIM + y]);
        }
    } else {
        __shared__ int h[NB];
        int j = b - NORM_BLOCKS - CONV_BLOCKS;     // chunk id 0..195
        int t = threadIdx.x;
        for (int i = t; i < NB; i += 256) h[i] = 0;
        __syncthreads();
        int base = j * CHUNK;
        #pragma unroll
        for (int k = 0; k < CHUNK / 256; k++) {
            int e = base + t + k * 256;
            if (e < N_EDGES) atomicAdd(&h[rows[e] >> BUCKET_SHIFT], 1);
        }
        __syncthreads();
        for (int i = t; i < NB; i += 256) gpartial[j * NB + i] = h[i];
    }
}

// ---------------------------------------------------------------------------
// Bucket scan (1 block): totals = sum_j gpartial[j][b]; exclusive scan ->
// bucket_base (392 entries) + bcursor seed; rowptr[N] = E.
// ---------------------------------------------------------------------------
__global__ __launch_bounds__(512) void bucket_scan_kernel(
    const int* __restrict__ gpartial, int* __restrict__ bucket_base,
    int* __restrict__ bcursor, int* __restrict__ rowptr) {
    __shared__ int s[512];
    int t = threadIdx.x;
    int total = 0;
    if (t < NB) {
        #pragma unroll 4
        for (int j = 0; j < NCHUNK; j++) total += gpartial[j * NB + t];
    }
    s[t] = total;
    __syncthreads();
    #pragma unroll
    for (int off = 1; off < 512; off <<= 1) {
        int u = (t >= off) ? s[t - off] : 0;
        __syncthreads();
        s[t] += u;
        __syncthreads();
    }
    if (t < NB) {
        int excl = s[t] - total;
        bucket_base[t] = excl;
        bcursor[t] = excl;
    }
    if (t == 0) { bucket_base[NB] = N_EDGES; rowptr[N_NODES] = N_EDGES; }
}

// ---------------------------------------------------------------------------
// Bucketize: compact each 4096-edge chunk into per-bucket LDS runs (offsets
// from gpartial), reserve global ranges via one atomic per bucket, copy out.
// Edge payload: word0 = col(16) | lrow(7) | bucket(9), word1 = fp32 val.
// ---------------------------------------------------------------------------
__global__ __launch_bounds__(512) void bucketize_kernel(
    const int* __restrict__ rows, const int* __restrict__ cols,
    const float* __restrict__ vals, const int* __restrict__ gpartial,
    int* __restrict__ bcursor, int2* __restrict__ edges) {
    __shared__ int ob[512];            // exclusive chunk-local bucket offsets
    __shared__ int c[NB];              // placement cursors
    __shared__ int g[NB];              // reserved global bases
    __shared__ int2 buf[CHUNK];        // 32 KB
    int t = threadIdx.x;
    int j = blockIdx.x;
    int base = j * CHUNK;
    int M = N_EDGES - base; if (M > CHUNK) M = CHUNK;
    int cnt = (t < NB) ? gpartial[j * NB + t] : 0;
    ob[t] = cnt;
    __syncthreads();
    #pragma unroll
    for (int off = 1; off < 512; off <<= 1) {
        int u = (t >= off) ? ob[t - off] : 0;
        __syncthreads();
        ob[t] += u;
        __syncthreads();
    }
    ob[t] -= cnt;  // exclusive (own slot only)
    if (t < NB) {
        c[t] = 0;
        g[t] = (cnt > 0) ? atomicAdd(&bcursor[t], cnt) : 0;
    }
    __syncthreads();
    #pragma unroll
    for (int k = 0; k < CHUNK / 512; k++) {
        int e = base + t + k * 512;
        if (e < N_EDGES) {
            int r = rows[e];
            int bb = r >> BUCKET_SHIFT;
            int p = ob[bb] + atomicAdd(&c[bb], 1);
            buf[p] = make_int2(cols[e] | ((r & 127) << 16) | (bb << 23),
                               __float_as_int(vals[e]));
        }
    }
    __syncthreads();
    for (int i = t; i < M; i += 512) {
        int2 e = buf[i];
        int bb = (int)((uint32)e.x >> 23);
        edges[g[bb] + (i - ob[bb])] = e;
    }
}

// ---------------------------------------------------------------------------
// Bucket sort: per-bucket LDS counting sort by local row, in place; ALSO
// emits rowptr for its 128 rows. Global-scratch fallback if bucket > CAP_B.
// ---------------------------------------------------------------------------
__global__ __launch_bounds__(256) void bucket_sort_kernel(
    const int* __restrict__ bucket_base, int2* __restrict__ edges,
    int2* __restrict__ scratch, int* __restrict__ rowptr) {
    __shared__ int2 buf[CAP_B];   // 20.5 KB
    __shared__ int2 buf2[CAP_B];  // 20.5 KB
    __shared__ int h[128], o[128], c[128];
    int b = blockIdx.x, t = threadIdx.x;
    int base = bucket_base[b];
    int cnt = bucket_base[b + 1] - base;
    bool fits = (cnt <= CAP_B);
    if (t < 128) h[t] = 0;
    __syncthreads();
    for (int i = t; i < cnt; i += 256) {
        int2 e = edges[base + i];
        if (fits) buf[i] = e; else scratch[base + i] = e;
        atomicAdd(&h[(e.x >> 16) & 127], 1);
    }
    __syncthreads();
    int valh = (t < 128) ? h[t] : 0;
    #pragma unroll
    for (int off = 1; off < 128; off <<= 1) {
        int u = (t >= off && t < 128) ? h[t - off] : 0;
        __syncthreads();
        if (t < 128) h[t] += u;
        __syncthreads();
    }
    if (t < 128) {
        o[t] = h[t] - valh;
        c[t] = 0;
        int i = (b << BUCKET_SHIFT) + t;
        if (i < N_NODES) rowptr[i] = base + h[t] - valh;
    }
    __syncthreads();
    for (int i = t; i < cnt; i += 256) {
        int2 e = fits ? buf[i] : scratch[base + i];
        int lr = (e.x >> 16) & 127;
        int p = o[lr] + atomicAdd(&c[lr], 1);
        if (fits) buf2[p] = e; else edges[base + p] = e;
    }
    __syncthreads();
    if (fits)
        for (int i = t; i < cnt; i += 256) edges[base + i] = buf2[i];
}

// ---------------------------------------------------------------------------
// Quad-row INT8 spmm accumulator: wave = 4 groups of 16 lanes; group g
// processes its own row, lane owns dims g16*8..g16*8+7 via uint2 = 8 int8
// bytes (8 B/lane: HALF the bytes of the bf16 path -- the gather is at a
// delivered-bytes roofline ~4.5 TB/s, so bytes/edge is the only lever).
// Edge value premultiplied by the column's row-scale (scales is a 200 KB
// L2-resident table). 8-wide edge unroll as before.
// ---------------------------------------------------------------------------
__device__ __forceinline__ void spmm_row4_q8(const uint2* __restrict__ xq2,
                                             const float* __restrict__ scales,
                                             const int2* __restrict__ edges,
                                             int start, int end, int lane,
                                             float A[8]) {
    const int g16 = lane & 15;    // lane-in-group
    const int bsrc = lane & 48;   // shfl source base for my group
    int cur = start;
    while (__any(cur < end)) {
        int n = end - cur;
        n = n < 0 ? 0 : (n > 16 ? 16 : n);
        int2 ev = make_int2(0, 0);
        float sc = 0.f;
        if (g16 < n) {
            ev = edges[cur + g16];
            sc = scales[ev.x & 0xFFFF];
        }
        int c = ev.x & 0xFFFF;
        float vs = __int_as_float(ev.y) * sc;   // v * row-scale, premerged
        int n0 = __shfl(n, 0, 64), n1 = __shfl(n, 16, 64);
        int n2 = __shfl(n, 32, 64), n3 = __shfl(n, 48, 64);
        int nm = max(max(n0, n1), max(n2, n3));
        int jm = (nm + 7) & ~7;
        for (int j = 0; j < jm; j += 8) {
            uint2 f[8];
            float vv[8];
            #pragma unroll
            for (int u = 0; u < 8; u++) {
                int cc = __shfl(c, bsrc + j + u, 64);
                vv[u] = __shfl(vs, bsrc + j + u, 64);
                f[u] = xq2[(size_t)cc * 16 + g16];
            }
            #pragma unroll
            for (int u = 0; u < 8; u++) {
                A[0] += vv[u] * ub0(f[u].x); A[1] += vv[u] * ub1(f[u].x);
                A[2] += vv[u] * ub2(f[u].x); A[3] += vv[u] * ub3(f[u].x);
                A[4] += vv[u] * ub0(f[u].y); A[5] += vv[u] * ub1(f[u].y);
                A[6] += vv[u] * ub2(f[u].y); A[7] += vv[u] * ub3(f[u].y);
            }
        }
        cur += n;
    }
}

// ---------------------------------------------------------------------------
// Quad-row bf16 spmm accumulator (unchanged R4): used for the second spmm
// (hw stays bf16 -- quantizing it would hit y directly).
// ---------------------------------------------------------------------------
__device__ __forceinline__ void spmm_row4(const uint4* __restrict__ feat4,
                                          const int2* __restrict__ edges,
                                          int start, int end, int lane,
                                          float A[8]) {
    const int g16 = lane & 15;    // lane-in-group
    const int bsrc = lane & 48;   // shfl source base for my group
    int cur = start;
    while (__any(cur < end)) {
        int n = end - cur;
        n = n < 0 ? 0 : (n > 16 ? 16 : n);
        int2 ev = make_int2(0, 0);
        if (g16 < n) ev = edges[cur + g16];
        int c = ev.x & 0xFFFF;
        float v = __int_as_float(ev.y);
        int n0 = __shfl(n, 0, 64), n1 = __shfl(n, 16, 64);
        int n2 = __shfl(n, 32, 64), n3 = __shfl(n, 48, 64);
        int nm = max(max(n0, n1), max(n2, n3));
        int jm = (nm + 7) & ~7;
        for (int j = 0; j < jm; j += 8) {
            uint4 f[8];
            float vv[8];
            #pragma unroll
            for (int u = 0; u < 8; u++) {
                int cc = __shfl(c, bsrc + j + u, 64);
                vv[u] = __shfl(v, bsrc + j + u, 64);
                f[u] = feat4[(size_t)cc * 16 + g16];
            }
            #pragma unroll
            for (int u = 0; u < 8; u++) {
                A[0] += vv[u] * bf_lo(f[u].x); A[1] += vv[u] * bf_hi(f[u].x);
                A[2] += vv[u] * bf_lo(f[u].y); A[3] += vv[u] * bf_hi(f[u].y);
                A[4] += vv[u] * bf_lo(f[u].z); A[5] += vv[u] * bf_hi(f[u].z);
                A[6] += vv[u] * bf_lo(f[u].w); A[7] += vv[u] * bf_hi(f[u].w);
            }
        }
        cur += n;
    }
}

// ---------------------------------------------------------------------------
// Fused SPMM + double GEMM per 64-row tile (512 thr, 8 waves), R4 structure:
//   phase 0: each wave gathers 8 rows (2 passes x 4 rows, quad-row, INT8
//            features) of agg1 = A @ x-hat into the LDS A-tile (bf16).
//   phase 1: h = relu(A @ W1 + b1) via MFMA, wave owns 32 h-cols.
//   phase 2: hw = h @ W2, wave owns 16 hw-cols. Written bf16.
// LDS 51.2 KB -> 3 blocks/CU (24 waves); VGPR budget 128 (launch_bounds 4).
// ---------------------------------------------------------------------------
__global__ __launch_bounds__(512, 4) void spmm_gemm_fused(
    const uint32* __restrict__ xq, const float* __restrict__ scales,
    const int* __restrict__ rowptr,
    const int2* __restrict__ edges, const ushort16* __restrict__ W1t,
    const ushort16* __restrict__ W2t, const float* __restrict__ b1,
    ushort16* __restrict__ hw) {
    __shared__ ushort16 a_s[64 * 136];  // 17.4 KB
    __shared__ ushort16 h_s[64 * 264];  // 33.8 KB
    const int tx = threadIdx.x;
    const int wave = tx >> 6, lane = tx & 63;
    const int quad = lane >> 4, l16 = lane & 15;
    const int row0 = blockIdx.x * 64;

    // Phase 0: gather 8 rows per wave (4 at a time, quad-row) into the A-tile
    for (int i = 0; i < 2; i++) {
        int r = wave * 8 + i * 4 + quad;
        int row = row0 + r;
        int s = 0, e = 0;
        if (row < N_NODES) { s = rowptr[row]; e = rowptr[row + 1]; }
        float A[8] = {0.f, 0.f, 0.f, 0.f, 0.f, 0.f, 0.f, 0.f};
        spmm_row4_q8((const uint2*)xq, scales, edges, s, e, lane, A);
        uint4 pk;
        pk.x = (uint32)f2bf(A[0]) | ((uint32)f2bf(A[1]) << 16);
        pk.y = (uint32)f2bf(A[2]) | ((uint32)f2bf(A[3]) << 16);
        pk.z = (uint32)f2bf(A[4]) | ((uint32)f2bf(A[5]) << 16);
        pk.w = (uint32)f2bf(A[6]) | ((uint32)f2bf(A[7]) << 16);
        *(uint4*)&a_s[r * 136 + l16 * 8] = pk;
    }

    // Preload stage-1 B fragments AFTER the gather (register pressure):
    // wave owns h-cols [wave*32, wave*32+32)
    short8 bfr1[2][4];  // [ct][kk]
    #pragma unroll
    for (int ct = 0; ct < 2; ct++)
        #pragma unroll
        for (int kk = 0; kk < 4; kk++)
            bfr1[ct][kk] = *(const short8*)
                &W1t[(wave * 32 + ct * 16 + l16) * 128 + kk * 32 + quad * 8];
    __syncthreads();

    // Phase 1: h = relu(A @ W1 + b1)
    floatx4 acc1[4][2];  // [rs][ct]
    #pragma unroll
    for (int rs = 0; rs < 4; rs++)
        #pragma unroll
        for (int ct = 0; ct < 2; ct++)
            #pragma unroll
            for (int j = 0; j < 4; j++) acc1[rs][ct][j] = 0.f;
    #pragma unroll
    for (int kk = 0; kk < 4; kk++) {
        #pragma unroll
        for (int rs = 0; rs < 4; rs++) {
            short8 af = *(const short8*)&a_s[(rs * 16 + l16) * 136 + kk * 32 + quad * 8];
            #pragma unroll
            for (int ct = 0; ct < 2; ct++)
                acc1[rs][ct] = __builtin_amdgcn_mfma_f32_16x16x32_bf16(
                    af, bfr1[ct][kk], acc1[rs][ct], 0, 0, 0);
        }
    }
    float bv[2];
    #pragma unroll
    for (int ct = 0; ct < 2; ct++) bv[ct] = b1[wave * 32 + ct * 16 + l16];
    #pragma unroll
    for (int rs = 0; rs < 4; rs++)
        #pragma unroll
        for (int ct = 0; ct < 2; ct++)
            #pragma unroll
            for (int reg = 0; reg < 4; reg++) {
                float v = acc1[rs][ct][reg] + bv[ct];
                v = v > 0.f ? v : 0.f;
                h_s[(rs * 16 + quad * 4 + reg) * 264 + wave * 32 + ct * 16 + l16] = f2bf(v);
            }

    // Preload stage-2 B fragments: wave owns hw-cols [wave*16, wave*16+16)
    short8 bfr2[8];
    #pragma unroll
    for (int kk = 0; kk < 8; kk++)
        bfr2[kk] = *(const short8*)
            &W2t[(wave * 16 + l16) * 256 + kk * 32 + quad * 8];
    __syncthreads();

    // Phase 2: hw = h @ W2
    floatx4 acc2[4];
    #pragma unroll
    for (int rs = 0; rs < 4; rs++)
        #pragma unroll
        for (int j = 0; j < 4; j++) acc2[rs][j] = 0.f;
    #pragma unroll
    for (int kk = 0; kk < 8; kk++) {
        #pragma unroll
        for (int rs = 0; rs < 4; rs++) {
            short8 af = *(const short8*)&h_s[(rs * 16 + l16) * 264 + kk * 32 + quad * 8];
            acc2[rs] = __builtin_amdgcn_mfma_f32_16x16x32_bf16(
                af, bfr2[kk], acc2[rs], 0, 0, 0);
        }
    }
    #pragma unroll
    for (int rs = 0; rs < 4; rs++)
        #pragma unroll
        for (int reg = 0; reg < 4; reg++) {
            int row = row0 + rs * 16 + quad * 4 + reg;
            if (row < N_NODES)
                hw[(size_t)row * 128 + wave * 16 + l16] = f2bf(acc2[rs][reg]);
        }
}

// ---------------------------------------------------------------------------
// Final spmm (unchanged R4): out = A @ hw + b2 (fp32 out). One wave per 4
// rows (quad-row). Grid exact: 3125 blocks x 4 waves x 4 rows = 50000.
// ---------------------------------------------------------------------------
__global__ __launch_bounds__(256, 4) void spmm_out_kernel(
    const uint32* __restrict__ feat, const int* __restrict__ rowptr,
    const int2* __restrict__ edges, const float* __restrict__ bias,
    float* __restrict__ out) {
    int w = (blockIdx.x * blockDim.x + threadIdx.x) >> 6;
    int lane = threadIdx.x & 63;
    int quad = lane >> 4, g16 = lane & 15;
    int row = w * 4 + quad;  // always < N_NODES (exact grid)
    int s = rowptr[row], e = rowptr[row + 1];
    float A[8] = {0.f, 0.f, 0.f, 0.f, 0.f, 0.f, 0.f, 0.f};
    spmm_row4((const uint4*)feat, edges, s, e, lane, A);
    float4 b0 = ((const float4*)bias)[g16 * 2];
    float4 b1 = ((const float4*)bias)[g16 * 2 + 1];
    ((float4*)out)[(size_t)row * 32 + g16 * 2] =
        make_float4(A[0] + b0.x, A[1] + b0.y, A[2] + b0.z, A[3] + b0.w);
    ((float4*)out)[(size_t)row * 32 + g16 * 2 + 1] =
        make_float4(A[4] + b1.x, A[5] + b1.y, A[6] + b1.z, A[7] + b1.w);
}

extern "C" void kernel_launch(void* const* d_in, const int* in_sizes, int n_in,
                              void* d_out, int out_size, void* d_ws, size_t ws_size,
                              hipStream_t stream) {
    const float* x = (const float*)d_in[0];
    const float* adj_vals = (const float*)d_in[1];
    const int* adj_row = (const int*)d_in[2];
    const int* adj_col = (const int*)d_in[3];
    const float* W1 = (const float*)d_in[4];
    const float* b1 = (const float*)d_in[5];
    const float* W2 = (const float*)d_in[6];
    const float* b2 = (const float*)d_in[7];
    float* out = (float*)d_out;

    // Workspace layout (~33 MB):
    char* ws = (char*)d_ws;
    unsigned short* xq = (unsigned short*)(ws + 0);      //  6.4 MB (int8 x-hat)
    float*    scales   = (float*)   (ws + 6400000);      //  200 KB (row scales)
    ushort16* hw       = (ushort16*)(ws + 6600000);      // 12.8 MB (bf16)
    int2*     edges    = (int2*)    (ws + 19400000);     //  6.4 MB
    int2*     scratch  = (int2*)    (ws + 25800000);     //  6.4 MB (fallback only)
    int*      gpartial = (int*)     (ws + 32200000);     //  306 KB
    int*      rowptr   = (int*)     (ws + 32507008);     //  200 KB
    int*      bbase    = (int*)     (ws + 32708000);     //  1.6 KB
    int*      bcursor  = (int*)     (ws + 32710048);     //  1.6 KB
    ushort16* W1t      = (ushort16*)(ws + 32712096);     //   64 KB
    ushort16* W2t      = (ushort16*)(ws + 32777632);     //   64 KB

    // 1. prep: int8 x-hat + scales + transposed bf16 weights + bucket hists
    hipLaunchKernelGGL(prep_kernel, dim3(NORM_BLOCKS + CONV_BLOCKS + NCHUNK),
                       dim3(256), 0, stream, x, xq, scales, W1, W2, W1t, W2t,
                       adj_row, gpartial);

    // 2. bucket bases (scan of 391 totals)
    hipLaunchKernelGGL(bucket_scan_kernel, dim3(1), dim3(512),
                       0, stream, gpartial, bbase, bcursor, rowptr);

    // 3. bucketize (coalesced) + per-bucket sort (emits rowptr)
    hipLaunchKernelGGL(bucketize_kernel, dim3(NCHUNK), dim3(512),
                       0, stream, adj_row, adj_col, adj_vals, gpartial, bcursor, edges);
    hipLaunchKernelGGL(bucket_sort_kernel, dim3(NB), dim3(256),
                       0, stream, bbase, edges, scratch, rowptr);

    // 4. hw = relu((A @ x-hat) @ W1 + b1) @ W2   [fused int8 spmm + MFMA]
    hipLaunchKernelGGL(spmm_gemm_fused, dim3((N_NODES + 63) / 64), dim3(512),
                       0, stream, (const uint32*)xq, scales, rowptr, edges,
                       W1t, W2t, b1, hw);

    // 5. out = A @ hw + b2
    hipLaunchKernelGGL(spmm_out_kernel, dim3(N_NODES / 16), dim3(256),
                       0, stream, (const uint32*)hw, rowptr, edges, b2, out);
}